// Round 8
// baseline (379.454 us; speedup 1.0000x reference)
//
#include <hip/hip_runtime.h>
#include <hip/hip_bf16.h>

// Problem constants
#define B_TOT  4096
#define M_TOT  65536
#define D_V    64
#define KD     96            // 64 (keys) + 32 (0.5*contexts); Q side pre-scaled by log2e
#define BQ     128           // q rows per block (4 waves x 32)
#define BN     64            // keys per inner tile
#define NQT    (B_TOT / BQ)  // 32
#define SHIFT2 23.0f         // fixed softmax shift in exp2 domain
#define NGRP   1024          // source 64-slot groups
#define NG_PAD 1056          // compacted group capacity (>= NC*ceil(NGRP/NC) for NC=16,32)

using short8   = __attribute__((ext_vector_type(8))) short;
using floatx4  = __attribute__((ext_vector_type(4))) float;
using int4v    = __attribute__((ext_vector_type(4))) int;

static __device__ __forceinline__ unsigned short f2bf(float f) {
  return __builtin_bit_cast(unsigned short, __float2bfloat16(f));
}

// truncation pack: two f32 -> one dword of bf16 (lo=a, hi=b), single v_perm_b32.
// Truncation bias cancels in the softmax ratio (verified: absmax 1.5e-5).
static __device__ __forceinline__ int pack_bf16(float a, float b) {
  return (int)__builtin_amdgcn_perm(__builtin_bit_cast(unsigned, b),
                                    __builtin_bit_cast(unsigned, a),
                                    0x07060302u);
}

static __device__ __forceinline__ floatx4 mfma16(short8 a, short8 b, floatx4 c) {
  return __builtin_amdgcn_mfma_f32_16x16x32_bf16(a, b, c, 0, 0, 0);
}

#define LOG2E 1.4426950408889634f

// ---- kernel 1: scan used slots (block 0) + qc pack (blocks 1..384) ----------
// Fused so the GPU is busy with qc while the single scan block runs.
// Block 0 also zeroes the flash tail-reduction counters.
// Masked slots contribute EXACTLY 0 to softmax (exp2(-1e9) underflows to 0 in
// fp32, same as the reference), so compacting to used slots is numerically
// exact up to fp32 summation order (~1e-7).

#define NB_QC 384   // 384 blocks x 1024 threads = 4096*96 qc elements

__global__ __launch_bounds__(1024) void
scan_qc(const int* __restrict__ used, const float* __restrict__ q,
        const float* __restrict__ ctx,
        int* __restrict__ off, unsigned long long* __restrict__ masks,
        int* __restrict__ gtotal, int* __restrict__ cnt,
        unsigned short* __restrict__ qc)
{
  const int bid = blockIdx.x;
  const int t = threadIdx.x;

  if (bid == 0) {
    __shared__ int s[NGRP];
    const int w = t >> 6, l = t & 63;
    if (t < NQT) cnt[t] = 0;          // tail counters for fused reduce
#pragma unroll 1
    for (int i0 = 0; i0 < 64; i0 += 8) {
      int v[8];
#pragma unroll
      for (int k = 0; k < 8; ++k)
        v[k] = used[(i0 + k) * 1024 + w * 64 + l];   // g = (i0+k)*16 + w
#pragma unroll
      for (int k = 0; k < 8; ++k) {
        unsigned long long m = __ballot(v[k] != 0);
        int g = (i0 + k) * 16 + w;
        if (l == 0) { masks[g] = m; s[g] = __popcll(m); }
      }
    }
    __syncthreads();
    const int c0 = s[t];
#pragma unroll 1
    for (int st = 1; st < NGRP; st <<= 1) {
      int add = (t >= st) ? s[t - st] : 0;
      __syncthreads();
      s[t] += add;
      __syncthreads();
    }
    off[t] = s[t] - c0;
    if (t == NGRP - 1) *gtotal = s[t];
  } else {
    int tt = (bid - 1) * 1024 + t;     // 4096*96 = 384*1024
    int b = tt / KD, j = tt % KD;
    float v = (j < 64) ? q[b * 64 + j] : 0.5f * ctx[b * 32 + (j - 64)];
    qc[tt] = f2bf(v * LOG2E);
  }
}

// ---- kernel 2: gather-prep into compacted fragment-linear layouts -----------
// blocks [0, NG_PAD): compacted K/ctx/V/bias dest groups (gather via off+masks)
// Blocks >= glim = NC*ceil(Gtot/NC) (never read by flash) return with no work;
// full-pad groups in [Gtot, glim) zero-fill without gathering.

template<int NC>
__global__ __launch_bounds__(256) void
prep2(const float* __restrict__ keys, const float* __restrict__ ctxs,
      const float* __restrict__ vals, const float* __restrict__ ts,
      const int* __restrict__ off, const unsigned long long* __restrict__ masks,
      const int* __restrict__ gtotal,
      unsigned short* __restrict__ kc2, unsigned short* __restrict__ vt2,
      float* __restrict__ biasc)
{
  const int bid = blockIdx.x;
  const int t = threadIdx.x;

  const int gq = bid;              // dest group
  const int total = *gtotal;
  const int Gtot = (total + 63) >> 6;
  int GPC = (Gtot + NC - 1) / NC;
  if (GPC < 1) GPC = 1;
  const int glim = NC * GPC;       // groups flash will actually read
  if (gq >= glim) return;

  if (gq * 64 >= total) {          // full pad group: zeros + -1e9 bias
    short8 z8;
#pragma unroll
    for (int j = 0; j < 8; ++j) z8[j] = 0;
    unsigned short* outk = kc2 + (size_t)gq * 6144;
#pragma unroll
    for (int p = 0; p < 3; ++p)
      *reinterpret_cast<short8*>(outk + p * 2048 + t * 8) = z8;
    unsigned short* outv = vt2 + (size_t)gq * 4096;
#pragma unroll
    for (int p = 0; p < 2; ++p)
      *reinterpret_cast<short8*>(outv + p * 2048 + t * 8) = z8;
    if (t < 64) biasc[gq * 64 + t] = -1e9f;
    return;
  }

  __shared__ float lk[64 * 65];    // K rows; reused for V rows
  __shared__ float lx[64 * 33];    // ctx rows
  __shared__ int sidx[64];

  // source index for each of this dest group's 64 slots
  if (t < 64) {
    int mP = gq * 64 + t, src = -1;
    if (mP < total) {
      int lo = 0, hi = NGRP - 1;
#pragma unroll 1
      while (lo < hi) {            // last g with off[g] <= mP
        int mid = (lo + hi + 1) >> 1;
        int ov = off[mid];
        if (ov <= mP) lo = mid; else hi = mid - 1;
      }
      int r = mP - off[lo];
      unsigned long long x = masks[lo];
#pragma unroll 1
      for (int k = 0; k < r; ++k) x &= x - 1;   // select r-th set bit
      src = lo * 64 + (int)__builtin_ctzll(x);
    }
    sidx[t] = src;
  }
  __syncthreads();

  const floatx4* kb4 = reinterpret_cast<const floatx4*>(keys);
  const floatx4* xb4 = reinterpret_cast<const floatx4*>(ctxs);
  const floatx4* vb4 = reinterpret_cast<const floatx4*>(vals);
  floatx4 z4; z4[0] = 0.f; z4[1] = 0.f; z4[2] = 0.f; z4[3] = 0.f;

  // gather K rows (64x64 f32) + ctx rows (64x32 f32); pad rows -> 0
#pragma unroll
  for (int i = 0; i < 4; ++i) {
    int idx4 = i * 256 + t;
    int row = idx4 >> 4, col = idx4 & 15;
    int s = sidx[row];
    floatx4 v = (s >= 0) ? kb4[(size_t)s * 16 + col] : z4;
    lk[row * 65 + col * 4 + 0] = v[0];
    lk[row * 65 + col * 4 + 1] = v[1];
    lk[row * 65 + col * 4 + 2] = v[2];
    lk[row * 65 + col * 4 + 3] = v[3];
  }
#pragma unroll
  for (int i = 0; i < 2; ++i) {
    int idx4 = i * 256 + t;
    int row = idx4 >> 3, col = idx4 & 7;
    int s = sidx[row];
    floatx4 v = (s >= 0) ? xb4[(size_t)s * 8 + col] : z4;
    lx[row * 33 + col * 4 + 0] = v[0];
    lx[row * 33 + col * 4 + 1] = v[1];
    lx[row * 33 + col * 4 + 2] = v[2];
    lx[row * 33 + col * 4 + 3] = v[3];
  }
  __syncthreads();

  // pack kc2 fragment-linear (same mapping as before, dest group gq)
  unsigned short* outk = kc2 + (size_t)gq * 6144;
#pragma unroll
  for (int p = 0; p < 3; ++p) {
    int o = p * 2048 + t * 8;
    int c = o >> 9;
    int lane = (o >> 3) & 63;
    int lqq = lane >> 4, lcc = lane & 15;
    int nt = c / 3, s = c - nt * 3;
    int ml = nt * 16 + lcc;
    short8 v;
#pragma unroll
    for (int j = 0; j < 8; ++j) {
      int kk = s * 32 + lqq * 8 + j;
      float f = (kk < 64) ? lk[ml * 65 + kk] : lx[ml * 33 + (kk - 64)];
      v[j] = (short)f2bf(f);
    }
    *reinterpret_cast<short8*>(outk + o) = v;
  }
  // bias for this dest group (pad -> -1e9 -> exp2 -> 0)
  if (t < 64) {
    int s = sidx[t];
    biasc[gq * 64 + t] =
        (s >= 0) ? (LOG2E * 0.3f * __expf(-0.1f * (1.0f - ts[s])) - SHIFT2)
                 : -1e9f;
  }
  __syncthreads();   // all kc2-pack reads of lk done before V overwrites it

  // gather V rows into lk
#pragma unroll
  for (int i = 0; i < 4; ++i) {
    int idx4 = i * 256 + t;
    int row = idx4 >> 4, col = idx4 & 15;
    int s = sidx[row];
    floatx4 v = (s >= 0) ? vb4[(size_t)s * 16 + col] : z4;
    lk[row * 65 + col * 4 + 0] = v[0];
    lk[row * 65 + col * 4 + 1] = v[1];
    lk[row * 65 + col * 4 + 2] = v[2];
    lk[row * 65 + col * 4 + 3] = v[3];
  }
  __syncthreads();

  // pack vt2 (B-operand of P*V, key-permutation baked in), dest group gq
  unsigned short* outv = vt2 + (size_t)gq * 4096;
#pragma unroll
  for (int p = 0; p < 2; ++p) {
    int o = p * 2048 + t * 8;
    int c2 = o >> 9;
    int lane = (o >> 3) & 63;
    int lqq = lane >> 4, lcc = lane & 15;
    int h = c2 >> 2, nd = c2 & 3;
    short8 wv;
#pragma unroll
    for (int j = 0; j < 8; ++j) {
      int mloc = h * 32 + ((j < 4) ? (lqq * 4 + j) : (16 + lqq * 4 + (j - 4)));
      wv[j] = (short)f2bf(lk[mloc * 65 + nd * 16 + lcc]);
    }
    *reinterpret_cast<short8*>(outv + o) = wv;
  }
}

// ---- kernel 3: flash attention + fused final reduction ----------------------
// grid (NQT, NC); block 256 = 4 waves; each wave owns 32 q rows (2 B-frags).
// Runs over the COMPACTED slot stream: NIT = GPC = ceil(Gtot/NC) groups per
// chunk (gtotal read at runtime; uniform across grid; grid static -> graph-
// capture safe). Software pipeline + setprio (R5) unchanged.
// R8: the LAST chunk-block per qt (device-scope atomic counter) performs the
// final cross-chunk reduction — bitwise-identical math to the old reduce_out
// kernel (same c-order float4 sums, same 1/l). Saves one kernel dispatch.

template<int NC>
__global__ __launch_bounds__(256, 4) void
flash_kernel(const unsigned short* __restrict__ qc,
             const unsigned short* __restrict__ kc2,
             const unsigned short* __restrict__ vt2,
             const float* __restrict__ biasc,
             const int* __restrict__ gtotal,
             float* __restrict__ opart, float* __restrict__ lpart,
             int* __restrict__ cnt, float* __restrict__ out)
{
  __shared__ __align__(16) unsigned short lds_kv[2 * 10240];  // 40960 B
  const int qt    = blockIdx.x;
  const int chunk = blockIdx.y;
  const int tid   = threadIdx.x;
  const int w     = tid >> 6;
  const int lane  = tid & 63;
  const int lq    = lane >> 4;
  const int lc    = lane & 15;

  const int total = *gtotal;
  const int Gtot  = (total + 63) >> 6;
  int GPC = (Gtot + NC - 1) / NC;
  if (GPC < 1) GPC = 1;
  const int NIT = GPC;                 // 64-key tiles for this chunk
  const int g0  = chunk * GPC;

  floatx4 zero; zero[0] = 0.f; zero[1] = 0.f; zero[2] = 0.f; zero[3] = 0.f;

  // Q fragments (B-operand): q-rows qt*128 + w*32 + a*16 + lc
  short8 qf[2][3];
#pragma unroll
  for (int a = 0; a < 2; ++a) {
    const unsigned short* qrp = qc + (size_t)(qt * BQ + w * 32 + a * 16 + lc) * KD + lq * 8;
    qf[a][0] = *reinterpret_cast<const short8*>(qrp);
    qf[a][1] = *reinterpret_cast<const short8*>(qrp + 32);
    qf[a][2] = *reinterpret_cast<const short8*>(qrp + 64);
  }

  short8 ones;
#pragma unroll
  for (int i = 0; i < 8; ++i) ones[i] = (short)0x3F80;  // bf16 1.0

  const float* bptr = biasc + (size_t)g0 * 64 + lq * 4;

  // cooperative stage of one 64-key group: 20 x 1KB pieces, 5 per wave
  auto stage = [&](int it, int buf) {
    const unsigned short* kg = kc2 + (size_t)(g0 + it) * 6144;
    const unsigned short* vg = vt2 + (size_t)(g0 + it) * 4096;
    unsigned short* lb = lds_kv + buf * 10240;
#pragma unroll
    for (int j5 = 0; j5 < 5; ++j5) {
      int j = w + j5 * 4;
      const unsigned short* src = (j < 12) ? (kg + j * 512) : (vg + (j - 12) * 512);
      __builtin_amdgcn_global_load_lds(
          (const __attribute__((address_space(1))) void*)(src + lane * 8),
          (__attribute__((address_space(3))) void*)(lb + j * 512),
          16, 0, 0);
    }
  };

  floatx4 o[2][4];
#pragma unroll
  for (int a = 0; a < 2; ++a)
#pragma unroll
    for (int nd = 0; nd < 4; ++nd) o[a][nd] = zero;
  floatx4 lacc[2] = {zero, zero};
  int4v pk[2][2];

  // QK + exp2 + pack phase (fills pk; accumulates row sums via ones-MFMA)
  auto qk_phase = [&](const unsigned short* lb, const float* bp) {
    floatx4 b4v[4];
#pragma unroll
    for (int nt = 0; nt < 4; ++nt)
      b4v[nt] = *reinterpret_cast<const floatx4*>(bp + nt * 16);
#pragma unroll
    for (int nt = 0; nt < 4; ++nt) {
      short8 k0 = *reinterpret_cast<const short8*>(lb + (nt * 3 + 0) * 512 + lane * 8);
      short8 k1 = *reinterpret_cast<const short8*>(lb + (nt * 3 + 1) * 512 + lane * 8);
      short8 k2 = *reinterpret_cast<const short8*>(lb + (nt * 3 + 2) * 512 + lane * 8);
#pragma unroll
      for (int a = 0; a < 2; ++a) {
        floatx4 acc = b4v[nt];
        __builtin_amdgcn_s_setprio(1);
        acc = mfma16(k0, qf[a][0], acc);
        acc = mfma16(k1, qf[a][1], acc);
        acc = mfma16(k2, qf[a][2], acc);
        __builtin_amdgcn_s_setprio(0);
        float p0 = __builtin_amdgcn_exp2f(acc[0]);
        float p1 = __builtin_amdgcn_exp2f(acc[1]);
        float p2 = __builtin_amdgcn_exp2f(acc[2]);
        float p3 = __builtin_amdgcn_exp2f(acc[3]);
        pk[a][nt >> 1][(nt & 1) * 2]     = pack_bf16(p0, p1);
        pk[a][nt >> 1][(nt & 1) * 2 + 1] = pack_bf16(p2, p3);
      }
    }
    __builtin_amdgcn_s_setprio(1);
#pragma unroll
    for (int a = 0; a < 2; ++a) {
      lacc[a] = mfma16(__builtin_bit_cast(short8, pk[a][0]), ones, lacc[a]);
      lacc[a] = mfma16(__builtin_bit_cast(short8, pk[a][1]), ones, lacc[a]);
    }
    __builtin_amdgcn_s_setprio(0);
  };

  // PV phase for the pk currently in registers, V frags from given buffer
  auto pv_phase = [&](const unsigned short* lb) {
    __builtin_amdgcn_s_setprio(1);
#pragma unroll
    for (int nd = 0; nd < 4; ++nd) {
      short8 v0 = *reinterpret_cast<const short8*>(lb + 6144 + nd * 512 + lane * 8);
      short8 v1 = *reinterpret_cast<const short8*>(lb + 6144 + (4 + nd) * 512 + lane * 8);
#pragma unroll
      for (int a = 0; a < 2; ++a) {
        o[a][nd] = mfma16(__builtin_bit_cast(short8, pk[a][0]), v0, o[a][nd]);
        o[a][nd] = mfma16(__builtin_bit_cast(short8, pk[a][1]), v1, o[a][nd]);
      }
    }
    __builtin_amdgcn_s_setprio(0);
  };

  // prologue (stage(1) safe even when NIT==1: group g0+1 <= NC*GPC < NG_PAD,
  // in-bounds; its data is only consumed when NIT >= 2)
  stage(0, 0);
  __syncthreads();                  // stage(0) landed
  stage(1, 1);
  qk_phase(lds_kv, bptr);
  bptr += BN;

#pragma unroll 1
  for (int it = 1; it < NIT; ++it) {
    // PV for iter it-1: buffer (it-1)&1 still valid (stage(it+1) not yet issued)
    pv_phase(lds_kv + ((it - 1) & 1) * 10240);
    __syncthreads();               // drains PV ds_reads + stage(it) vmcnt
    if (it + 1 < NIT) stage(it + 1, (it + 1) & 1);
    qk_phase(lds_kv + (it & 1) * 10240, bptr);
    bptr += BN;
  }
  pv_phase(lds_kv + ((NIT - 1) & 1) * 10240);

  // epilogue: write partial O and l
  const int pb = qt * NC + chunk;
  float* op = opart + (size_t)pb * BQ * D_V;
#pragma unroll
  for (int a = 0; a < 2; ++a) {
    const int rbase = w * 32 + a * 16 + lq * 4;
#pragma unroll
    for (int nd = 0; nd < 4; ++nd)
#pragma unroll
      for (int r = 0; r < 4; ++r)
        op[(rbase + r) * D_V + nd * 16 + lc] = o[a][nd][r];
    // lacc C-layout: lane (lq,lc) reg r holds l[q-row = lq*4+r] (same across lc)
    if (lc == 0) {
      float* lp = lpart + (size_t)pb * BQ;
#pragma unroll
      for (int r = 0; r < 4; ++r) lp[rbase + r] = lacc[a][r];
    }
  }

  // ---- fused tail reduction: last chunk-block for this qt reduces ----------
  __threadfence();                 // partials visible device-wide
  __syncthreads();                 // all threads' stores issued
  int* sold = reinterpret_cast<int*>(lds_kv);        // lds_kv reuse (safe after barrier)
  float* sinv = reinterpret_cast<float*>(lds_kv) + 16;
  if (tid == 0) *sold = atomicAdd(&cnt[qt], 1);
  __syncthreads();
  if (*sold == NC - 1) {
    __threadfence();               // acquire side: see other blocks' partials
    if (tid < BQ) {
      float s = 0.f;
#pragma unroll 1
      for (int c = 0; c < NC; ++c) s += lpart[(size_t)(qt * NC + c) * BQ + tid];
      sinv[tid] = 1.0f / s;
    }
    __syncthreads();
    const floatx4* op4 = reinterpret_cast<const floatx4*>(opart);
#pragma unroll
    for (int k = 0; k < 8; ++k) {
      int u = k * 256 + tid;       // 0..2047 = BQ*16 float4s
      int r = u >> 4, d4 = u & 15;
      floatx4 os = zero;
#pragma unroll 1
      for (int c = 0; c < NC; ++c)
        os += op4[(size_t)((qt * NC + c) * BQ + r) * 16 + d4];
      float inv = sinv[r];
      reinterpret_cast<floatx4*>(out)[(size_t)(qt * BQ + r) * 16 + d4] = os * inv;
    }
  }
}

// ---- launcher ---------------------------------------------------------------

template<int NC>
static void launch_all(const float* query, const float* context, const float* keys,
                       const float* values, const float* contexts, const float* ts,
                       const int* used, float* out, char* ws, hipStream_t stream) {
  unsigned short* qc   = (unsigned short*)ws;  ws += (size_t)B_TOT * KD * 2;
  unsigned short* kc2c = (unsigned short*)ws;  ws += (size_t)NG_PAD * 6144 * 2;
  unsigned short* vt2c = (unsigned short*)ws;  ws += (size_t)NG_PAD * 4096 * 2;
  float* biasc = (float*)ws;                   ws += (size_t)NG_PAD * 64 * 4;
  int* off     = (int*)ws;                     ws += (size_t)NGRP * 4;
  unsigned long long* masks = (unsigned long long*)ws;  ws += (size_t)NGRP * 8;
  int* gtotal  = (int*)ws;                     ws += 16;
  int* cnt     = (int*)ws;                     ws += (size_t)NQT * 4;
  float* opart = (float*)ws;                   ws += (size_t)NC * B_TOT * D_V * 4;
  float* lpart = (float*)ws;

  scan_qc<<<1 + NB_QC, 1024, 0, stream>>>(used, query, context,
                                          off, masks, gtotal, cnt, qc);

  prep2<NC><<<NG_PAD, 256, 0, stream>>>(
      keys, contexts, values, ts, off, masks, gtotal, kc2c, vt2c, biasc);

  dim3 grid(NQT, NC);
  flash_kernel<NC><<<grid, 256, 0, stream>>>(qc, kc2c, vt2c, biasc, gtotal,
                                             opart, lpart, cnt, out);
}

extern "C" void kernel_launch(void* const* d_in, const int* in_sizes, int n_in,
                              void* d_out, int out_size, void* d_ws, size_t ws_size,
                              hipStream_t stream) {
  const float* query    = (const float*)d_in[0];
  const float* context  = (const float*)d_in[1];
  const float* keys     = (const float*)d_in[2];
  const float* values   = (const float*)d_in[3];
  const float* contexts = (const float*)d_in[4];
  const float* ts       = (const float*)d_in[5];
  const int*   used     = (const int*)d_in[6];
  float* out = (float*)d_out;
  char* ws = (char*)d_ws;

  const size_t fixed = (size_t)B_TOT * KD * 2 + (size_t)NG_PAD * 6144 * 2 +
                       (size_t)NG_PAD * 4096 * 2 + (size_t)NG_PAD * 64 * 4 +
                       (size_t)NGRP * 4 + (size_t)NGRP * 8 + 16 + (size_t)NQT * 4;
  const size_t need32 = fixed + 32ull * ((size_t)B_TOT * D_V * 4 + (size_t)B_TOT * 4);

  if (ws_size >= need32)
    launch_all<32>(query, context, keys, values, contexts, ts, used, out, ws, stream);
  else
    launch_all<16>(query, context, keys, values, contexts, ts, used, out, ws, stream);
}

// Round 10
// 173.664 us; speedup vs baseline: 2.1850x; 2.1850x over previous
//
#include <hip/hip_runtime.h>
#include <hip/hip_bf16.h>

// Problem constants
#define B_TOT  4096
#define M_TOT  65536
#define D_V    64
#define KD     96            // 64 (keys) + 32 (0.5*contexts); Q side pre-scaled by log2e
#define BQ     128           // q rows per block (4 waves x 32)
#define BN     64            // keys per inner tile
#define NQT    (B_TOT / BQ)  // 32
#define SHIFT2 23.0f         // fixed softmax shift in exp2 domain
#define NGRP   1024          // source 64-slot groups
#define NG_PAD 1056          // compacted group capacity (>= NC*ceil(NGRP/NC) for NC=16,32)

using short8   = __attribute__((ext_vector_type(8))) short;
using floatx4  = __attribute__((ext_vector_type(4))) float;
using int4v    = __attribute__((ext_vector_type(4))) int;

static __device__ __forceinline__ unsigned short f2bf(float f) {
  return __builtin_bit_cast(unsigned short, __float2bfloat16(f));
}

// truncation pack: two f32 -> one dword of bf16 (lo=a, hi=b), single v_perm_b32.
// Truncation bias cancels in the softmax ratio (verified: absmax 1.5e-5).
static __device__ __forceinline__ int pack_bf16(float a, float b) {
  return (int)__builtin_amdgcn_perm(__builtin_bit_cast(unsigned, b),
                                    __builtin_bit_cast(unsigned, a),
                                    0x07060302u);
}

static __device__ __forceinline__ floatx4 mfma16(short8 a, short8 b, floatx4 c) {
  return __builtin_amdgcn_mfma_f32_16x16x32_bf16(a, b, c, 0, 0, 0);
}

#define LOG2E 1.4426950408889634f

// ---- kernel 1: scan used slots + emit srcidx (block 0) + qc pack ------------
// Block 0: ballot masks per 64-group, LDS prefix scan, then each thread walks
// its group's mask bits and writes the COMPACTED source-index list srcidx
// (removes prep2's per-row binary search + serial bit-select). Blocks 1..384
// pack qc concurrently. Masked slots contribute EXACTLY 0 to softmax
// (exp2(-1e9) underflows to 0 in fp32, same as the reference), so compaction
// is numerically exact up to fp32 summation order (~1e-7).

#define NB_QC 384   // 384 blocks x 1024 threads = 4096*96 qc elements

__global__ __launch_bounds__(1024) void
scan_qc(const int* __restrict__ used, const float* __restrict__ q,
        const float* __restrict__ ctx,
        int* __restrict__ srcidx, int* __restrict__ gtotal,
        unsigned short* __restrict__ qc)
{
  const int bid = blockIdx.x;
  const int t = threadIdx.x;

  if (bid == 0) {
    __shared__ int s[NGRP];
    __shared__ unsigned long long smask[NGRP];
    const int w = t >> 6, l = t & 63;
#pragma unroll 1
    for (int i0 = 0; i0 < 64; i0 += 8) {       // 8-deep load batching (R7)
      int v[8];
#pragma unroll
      for (int k = 0; k < 8; ++k)
        v[k] = used[(i0 + k) * 1024 + w * 64 + l];   // g = (i0+k)*16 + w
#pragma unroll
      for (int k = 0; k < 8; ++k) {
        unsigned long long m = __ballot(v[k] != 0);
        int g = (i0 + k) * 16 + w;
        if (l == 0) { smask[g] = m; s[g] = __popcll(m); }
      }
    }
    __syncthreads();
    const int c0 = s[t];
#pragma unroll 1
    for (int st = 1; st < NGRP; st <<= 1) {
      int add = (t >= st) ? s[t - st] : 0;
      __syncthreads();
      s[t] += add;
      __syncthreads();
    }
    // emit compacted source indices for group t
    int base = s[t] - c0;                       // exclusive offset
    unsigned long long x = smask[t];
#pragma unroll 1
    while (x) {
      srcidx[base++] = t * 64 + (int)__builtin_ctzll(x);
      x &= x - 1;
    }
    if (t == NGRP - 1) *gtotal = s[t];
  } else {
    int tt = (bid - 1) * 1024 + t;     // 4096*96 = 384*1024
    int b = tt / KD, j = tt % KD;
    float v = (j < 64) ? q[b * 64 + j] : 0.5f * ctx[b * 32 + (j - 64)];
    qc[tt] = f2bf(v * LOG2E);
  }
}

// ---- kernel 2: gather-prep into compacted fragment-linear layouts -----------
// blocks [0, NG_PAD): compacted K/ctx/V/bias dest groups (gather via srcidx).
// Blocks >= glim = NC*ceil(Gtot/NC) (never read by flash) return with no work;
// full-pad groups in [Gtot, glim) zero-fill without gathering.

template<int NC>
__global__ __launch_bounds__(256) void
prep2(const float* __restrict__ keys, const float* __restrict__ ctxs,
      const float* __restrict__ vals, const float* __restrict__ ts,
      const int* __restrict__ srcidx, const int* __restrict__ gtotal,
      unsigned short* __restrict__ kc2, unsigned short* __restrict__ vt2,
      float* __restrict__ biasc)
{
  const int bid = blockIdx.x;
  const int t = threadIdx.x;

  const int gq = bid;              // dest group
  const int total = *gtotal;
  const int Gtot = (total + 63) >> 6;
  int GPC = (Gtot + NC - 1) / NC;
  if (GPC < 1) GPC = 1;
  const int glim = NC * GPC;       // groups flash will actually read
  if (gq >= glim) return;

  if (gq * 64 >= total) {          // full pad group: zeros + -1e9 bias
    short8 z8;
#pragma unroll
    for (int j = 0; j < 8; ++j) z8[j] = 0;
    unsigned short* outk = kc2 + (size_t)gq * 6144;
#pragma unroll
    for (int p = 0; p < 3; ++p)
      *reinterpret_cast<short8*>(outk + p * 2048 + t * 8) = z8;
    unsigned short* outv = vt2 + (size_t)gq * 4096;
#pragma unroll
    for (int p = 0; p < 2; ++p)
      *reinterpret_cast<short8*>(outv + p * 2048 + t * 8) = z8;
    if (t < 64) biasc[gq * 64 + t] = -1e9f;
    return;
  }

  __shared__ float lk[64 * 65];    // K rows; reused for V rows
  __shared__ float lx[64 * 33];    // ctx rows
  __shared__ int sidx[64];

  // source index for each of this dest group's 64 slots (coalesced load)
  if (t < 64) {
    int mP = gq * 64 + t;
    sidx[t] = (mP < total) ? srcidx[mP] : -1;
  }
  __syncthreads();

  const floatx4* kb4 = reinterpret_cast<const floatx4*>(keys);
  const floatx4* xb4 = reinterpret_cast<const floatx4*>(ctxs);
  const floatx4* vb4 = reinterpret_cast<const floatx4*>(vals);
  floatx4 z4; z4[0] = 0.f; z4[1] = 0.f; z4[2] = 0.f; z4[3] = 0.f;

  // gather K rows (64x64 f32) + ctx rows (64x32 f32); pad rows -> 0
#pragma unroll
  for (int i = 0; i < 4; ++i) {
    int idx4 = i * 256 + t;
    int row = idx4 >> 4, col = idx4 & 15;
    int s = sidx[row];
    floatx4 v = (s >= 0) ? kb4[(size_t)s * 16 + col] : z4;
    lk[row * 65 + col * 4 + 0] = v[0];
    lk[row * 65 + col * 4 + 1] = v[1];
    lk[row * 65 + col * 4 + 2] = v[2];
    lk[row * 65 + col * 4 + 3] = v[3];
  }
#pragma unroll
  for (int i = 0; i < 2; ++i) {
    int idx4 = i * 256 + t;
    int row = idx4 >> 3, col = idx4 & 7;
    int s = sidx[row];
    floatx4 v = (s >= 0) ? xb4[(size_t)s * 8 + col] : z4;
    lx[row * 33 + col * 4 + 0] = v[0];
    lx[row * 33 + col * 4 + 1] = v[1];
    lx[row * 33 + col * 4 + 2] = v[2];
    lx[row * 33 + col * 4 + 3] = v[3];
  }
  __syncthreads();

  // pack kc2 fragment-linear (same mapping as before, dest group gq)
  unsigned short* outk = kc2 + (size_t)gq * 6144;
#pragma unroll
  for (int p = 0; p < 3; ++p) {
    int o = p * 2048 + t * 8;
    int c = o >> 9;
    int lane = (o >> 3) & 63;
    int lqq = lane >> 4, lcc = lane & 15;
    int nt = c / 3, s = c - nt * 3;
    int ml = nt * 16 + lcc;
    short8 v;
#pragma unroll
    for (int j = 0; j < 8; ++j) {
      int kk = s * 32 + lqq * 8 + j;
      float f = (kk < 64) ? lk[ml * 65 + kk] : lx[ml * 33 + (kk - 64)];
      v[j] = (short)f2bf(f);
    }
    *reinterpret_cast<short8*>(outk + o) = v;
  }
  // bias for this dest group (pad -> -1e9 -> exp2 -> 0)
  if (t < 64) {
    int s = sidx[t];
    biasc[gq * 64 + t] =
        (s >= 0) ? (LOG2E * 0.3f * __expf(-0.1f * (1.0f - ts[s])) - SHIFT2)
                 : -1e9f;
  }
  __syncthreads();   // all kc2-pack reads of lk done before V overwrites it

  // gather V rows into lk
#pragma unroll
  for (int i = 0; i < 4; ++i) {
    int idx4 = i * 256 + t;
    int row = idx4 >> 4, col = idx4 & 15;
    int s = sidx[row];
    floatx4 v = (s >= 0) ? vb4[(size_t)s * 16 + col] : z4;
    lk[row * 65 + col * 4 + 0] = v[0];
    lk[row * 65 + col * 4 + 1] = v[1];
    lk[row * 65 + col * 4 + 2] = v[2];
    lk[row * 65 + col * 4 + 3] = v[3];
  }
  __syncthreads();

  // pack vt2 (B-operand of P*V, key-permutation baked in), dest group gq
  unsigned short* outv = vt2 + (size_t)gq * 4096;
#pragma unroll
  for (int p = 0; p < 2; ++p) {
    int o = p * 2048 + t * 8;
    int c2 = o >> 9;
    int lane = (o >> 3) & 63;
    int lqq = lane >> 4, lcc = lane & 15;
    int h = c2 >> 2, nd = c2 & 3;
    short8 wv;
#pragma unroll
    for (int j = 0; j < 8; ++j) {
      int mloc = h * 32 + ((j < 4) ? (lqq * 4 + j) : (16 + lqq * 4 + (j - 4)));
      wv[j] = (short)f2bf(lk[mloc * 65 + nd * 16 + lcc]);
    }
    *reinterpret_cast<short8*>(outv + o) = wv;
  }
}

// ---- kernel 3: flash attention (R7-proven structure) ------------------------
// grid (NQT, NC); block 256 = 4 waves; each wave owns 32 q rows (2 B-frags).
// Runs over the COMPACTED slot stream: NIT = GPC = ceil(Gtot/NC) groups per
// chunk (gtotal read at runtime; uniform across grid; grid static -> graph-
// capture safe). Software pipeline + setprio (R5). NO in-kernel device fences
// or fused tail (R8 lesson: per-block threadfence = L2 writeback storm; the
// 32-block tail serializes the reduction — kernel-boundary sync is cheaper).

template<int NC>
__global__ __launch_bounds__(256, 4) void
flash_kernel(const unsigned short* __restrict__ qc,
             const unsigned short* __restrict__ kc2,
             const unsigned short* __restrict__ vt2,
             const float* __restrict__ biasc,
             const int* __restrict__ gtotal,
             float* __restrict__ opart, float* __restrict__ lpart)
{
  __shared__ __align__(16) unsigned short lds_kv[2 * 10240];  // 40960 B
  const int qt    = blockIdx.x;
  const int chunk = blockIdx.y;
  const int tid   = threadIdx.x;
  const int w     = tid >> 6;
  const int lane  = tid & 63;
  const int lq    = lane >> 4;
  const int lc    = lane & 15;

  const int total = *gtotal;
  const int Gtot  = (total + 63) >> 6;
  int GPC = (Gtot + NC - 1) / NC;
  if (GPC < 1) GPC = 1;
  const int NIT = GPC;                 // 64-key tiles for this chunk
  const int g0  = chunk * GPC;

  floatx4 zero; zero[0] = 0.f; zero[1] = 0.f; zero[2] = 0.f; zero[3] = 0.f;

  // Q fragments (B-operand): q-rows qt*128 + w*32 + a*16 + lc
  short8 qf[2][3];
#pragma unroll
  for (int a = 0; a < 2; ++a) {
    const unsigned short* qrp = qc + (size_t)(qt * BQ + w * 32 + a * 16 + lc) * KD + lq * 8;
    qf[a][0] = *reinterpret_cast<const short8*>(qrp);
    qf[a][1] = *reinterpret_cast<const short8*>(qrp + 32);
    qf[a][2] = *reinterpret_cast<const short8*>(qrp + 64);
  }

  short8 ones;
#pragma unroll
  for (int i = 0; i < 8; ++i) ones[i] = (short)0x3F80;  // bf16 1.0

  const float* bptr = biasc + (size_t)g0 * 64 + lq * 4;

  // cooperative stage of one 64-key group: 20 x 1KB pieces, 5 per wave
  auto stage = [&](int it, int buf) {
    const unsigned short* kg = kc2 + (size_t)(g0 + it) * 6144;
    const unsigned short* vg = vt2 + (size_t)(g0 + it) * 4096;
    unsigned short* lb = lds_kv + buf * 10240;
#pragma unroll
    for (int j5 = 0; j5 < 5; ++j5) {
      int j = w + j5 * 4;
      const unsigned short* src = (j < 12) ? (kg + j * 512) : (vg + (j - 12) * 512);
      __builtin_amdgcn_global_load_lds(
          (const __attribute__((address_space(1))) void*)(src + lane * 8),
          (__attribute__((address_space(3))) void*)(lb + j * 512),
          16, 0, 0);
    }
  };

  floatx4 o[2][4];
#pragma unroll
  for (int a = 0; a < 2; ++a)
#pragma unroll
    for (int nd = 0; nd < 4; ++nd) o[a][nd] = zero;
  floatx4 lacc[2] = {zero, zero};
  int4v pk[2][2];

  // QK + exp2 + pack phase (fills pk; accumulates row sums via ones-MFMA)
  auto qk_phase = [&](const unsigned short* lb, const float* bp) {
    floatx4 b4v[4];
#pragma unroll
    for (int nt = 0; nt < 4; ++nt)
      b4v[nt] = *reinterpret_cast<const floatx4*>(bp + nt * 16);
#pragma unroll
    for (int nt = 0; nt < 4; ++nt) {
      short8 k0 = *reinterpret_cast<const short8*>(lb + (nt * 3 + 0) * 512 + lane * 8);
      short8 k1 = *reinterpret_cast<const short8*>(lb + (nt * 3 + 1) * 512 + lane * 8);
      short8 k2 = *reinterpret_cast<const short8*>(lb + (nt * 3 + 2) * 512 + lane * 8);
#pragma unroll
      for (int a = 0; a < 2; ++a) {
        floatx4 acc = b4v[nt];
        __builtin_amdgcn_s_setprio(1);
        acc = mfma16(k0, qf[a][0], acc);
        acc = mfma16(k1, qf[a][1], acc);
        acc = mfma16(k2, qf[a][2], acc);
        __builtin_amdgcn_s_setprio(0);
        float p0 = __builtin_amdgcn_exp2f(acc[0]);
        float p1 = __builtin_amdgcn_exp2f(acc[1]);
        float p2 = __builtin_amdgcn_exp2f(acc[2]);
        float p3 = __builtin_amdgcn_exp2f(acc[3]);
        pk[a][nt >> 1][(nt & 1) * 2]     = pack_bf16(p0, p1);
        pk[a][nt >> 1][(nt & 1) * 2 + 1] = pack_bf16(p2, p3);
      }
    }
    __builtin_amdgcn_s_setprio(1);
#pragma unroll
    for (int a = 0; a < 2; ++a) {
      lacc[a] = mfma16(__builtin_bit_cast(short8, pk[a][0]), ones, lacc[a]);
      lacc[a] = mfma16(__builtin_bit_cast(short8, pk[a][1]), ones, lacc[a]);
    }
    __builtin_amdgcn_s_setprio(0);
  };

  // PV phase for the pk currently in registers, V frags from given buffer
  auto pv_phase = [&](const unsigned short* lb) {
    __builtin_amdgcn_s_setprio(1);
#pragma unroll
    for (int nd = 0; nd < 4; ++nd) {
      short8 v0 = *reinterpret_cast<const short8*>(lb + 6144 + nd * 512 + lane * 8);
      short8 v1 = *reinterpret_cast<const short8*>(lb + 6144 + (4 + nd) * 512 + lane * 8);
#pragma unroll
      for (int a = 0; a < 2; ++a) {
        o[a][nd] = mfma16(__builtin_bit_cast(short8, pk[a][0]), v0, o[a][nd]);
        o[a][nd] = mfma16(__builtin_bit_cast(short8, pk[a][1]), v1, o[a][nd]);
      }
    }
    __builtin_amdgcn_s_setprio(0);
  };

  // prologue (stage(1) safe even when NIT==1: group g0+1 <= NC*GPC < NG_PAD,
  // in-bounds; its data is only consumed when NIT >= 2)
  stage(0, 0);
  __syncthreads();                  // stage(0) landed
  stage(1, 1);
  qk_phase(lds_kv, bptr);
  bptr += BN;

#pragma unroll 1
  for (int it = 1; it < NIT; ++it) {
    // PV for iter it-1: buffer (it-1)&1 still valid (stage(it+1) not yet issued)
    pv_phase(lds_kv + ((it - 1) & 1) * 10240);
    __syncthreads();               // drains PV ds_reads + stage(it) vmcnt
    if (it + 1 < NIT) stage(it + 1, (it + 1) & 1);
    qk_phase(lds_kv + (it & 1) * 10240, bptr);
    bptr += BN;
  }
  pv_phase(lds_kv + ((NIT - 1) & 1) * 10240);

  // epilogue: write partial O and l
  const int pb = qt * NC + chunk;
  float* op = opart + (size_t)pb * BQ * D_V;
#pragma unroll
  for (int a = 0; a < 2; ++a) {
    const int rbase = w * 32 + a * 16 + lq * 4;
#pragma unroll
    for (int nd = 0; nd < 4; ++nd)
#pragma unroll
      for (int r = 0; r < 4; ++r)
        op[(rbase + r) * D_V + nd * 16 + lc] = o[a][nd][r];
    // lacc C-layout: lane (lq,lc) reg r holds l[q-row = lq*4+r] (same across lc)
    if (lc == 0) {
      float* lp = lpart + (size_t)pb * BQ;
#pragma unroll
      for (int r = 0; r < 4; ++r) lp[rbase + r] = lacc[a][r];
    }
  }
}

// ---- final reduction (float4-vectorized) ------------------------------------

template<int NC>
__global__ void reduce_out(const float* __restrict__ opart, const float* __restrict__ lpart,
                           float* __restrict__ out) {
  int t = blockIdx.x * 256 + threadIdx.x;   // 65536 float4s total
  int d4 = t & 15;
  int b = t >> 4;            // q-row 0..4095
  int qt = b >> 7, r = b & 127;
  const floatx4* op4 = reinterpret_cast<const floatx4*>(opart);
  floatx4 os; os[0] = 0.f; os[1] = 0.f; os[2] = 0.f; os[3] = 0.f;
  float ls = 0.f;
#pragma unroll
  for (int c = 0; c < NC; ++c) {
    int row = (qt * NC + c) * BQ + r;
    os += op4[(size_t)row * 16 + d4];
    ls += lpart[row];
  }
  float inv = 1.0f / ls;
  reinterpret_cast<floatx4*>(out)[t] = os * inv;
}

// ---- launcher ---------------------------------------------------------------

template<int NC>
static void launch_all(const float* query, const float* context, const float* keys,
                       const float* values, const float* contexts, const float* ts,
                       const int* used, float* out, char* ws, hipStream_t stream) {
  unsigned short* qc   = (unsigned short*)ws;  ws += (size_t)B_TOT * KD * 2;
  unsigned short* kc2c = (unsigned short*)ws;  ws += (size_t)NG_PAD * 6144 * 2;
  unsigned short* vt2c = (unsigned short*)ws;  ws += (size_t)NG_PAD * 4096 * 2;
  float* biasc = (float*)ws;                   ws += (size_t)NG_PAD * 64 * 4;
  int* srcidx  = (int*)ws;                     ws += (size_t)M_TOT * 4;
  int* gtotal  = (int*)ws;                     ws += 16;
  float* opart = (float*)ws;                   ws += (size_t)NC * B_TOT * D_V * 4;
  float* lpart = (float*)ws;

  scan_qc<<<1 + NB_QC, 1024, 0, stream>>>(used, query, context,
                                          srcidx, gtotal, qc);

  prep2<NC><<<NG_PAD, 256, 0, stream>>>(
      keys, contexts, values, ts, srcidx, gtotal, kc2c, vt2c, biasc);

  dim3 grid(NQT, NC);
  flash_kernel<NC><<<grid, 256, 0, stream>>>(qc, kc2c, vt2c, biasc, gtotal,
                                             opart, lpart);

  reduce_out<NC><<<(B_TOT * D_V / 4) / 256, 256, 0, stream>>>(opart, lpart, out);
}

extern "C" void kernel_launch(void* const* d_in, const int* in_sizes, int n_in,
                              void* d_out, int out_size, void* d_ws, size_t ws_size,
                              hipStream_t stream) {
  const float* query    = (const float*)d_in[0];
  const float* context  = (const float*)d_in[1];
  const float* keys     = (const float*)d_in[2];
  const float* values   = (const float*)d_in[3];
  const float* contexts = (const float*)d_in[4];
  const float* ts       = (const float*)d_in[5];
  const int*   used     = (const int*)d_in[6];
  float* out = (float*)d_out;
  char* ws = (char*)d_ws;

  const size_t fixed = (size_t)B_TOT * KD * 2 + (size_t)NG_PAD * 6144 * 2 +
                       (size_t)NG_PAD * 4096 * 2 + (size_t)NG_PAD * 64 * 4 +
                       (size_t)M_TOT * 4 + 16;
  const size_t need32 = fixed + 32ull * ((size_t)B_TOT * D_V * 4 + (size_t)B_TOT * 4);

  if (ws_size >= need32)
    launch_all<32>(query, context, keys, values, contexts, ts, used, out, ws, stream);
  else
    launch_all<16>(query, context, keys, values, contexts, ts, used, out, ws, stream);
}

// Round 11
// 165.823 us; speedup vs baseline: 2.2883x; 1.0473x over previous
//
#include <hip/hip_runtime.h>
#include <hip/hip_bf16.h>

// Problem constants
#define B_TOT  4096
#define M_TOT  65536
#define D_V    64
#define KD     96            // 64 (keys) + 32 (0.5*contexts); Q side pre-scaled by log2e
#define BQ     128           // q rows per block (4 waves x 32)
#define BN     64            // keys per inner tile
#define NQT    (B_TOT / BQ)  // 32
#define SHIFT2 23.0f         // fixed softmax shift in exp2 domain
#define NGRP   1024          // source 64-slot groups
#define NG_PAD 1056          // compacted group capacity (>= NC*ceil(NGRP/NC) for NC=16,32)
#define NB_QC  1536          // qc-pack blocks appended to prep3 grid (1536*256 = 4096*96)

using short8   = __attribute__((ext_vector_type(8))) short;
using floatx4  = __attribute__((ext_vector_type(4))) float;
using int4v    = __attribute__((ext_vector_type(4))) int;

static __device__ __forceinline__ unsigned short f2bf(float f) {
  return __builtin_bit_cast(unsigned short, __float2bfloat16(f));
}

// truncation pack: two f32 -> one dword of bf16 (lo=a, hi=b), single v_perm_b32.
// Truncation bias cancels in the softmax ratio (verified: absmax 1.5e-5).
static __device__ __forceinline__ int pack_bf16(float a, float b) {
  return (int)__builtin_amdgcn_perm(__builtin_bit_cast(unsigned, b),
                                    __builtin_bit_cast(unsigned, a),
                                    0x07060302u);
}

static __device__ __forceinline__ floatx4 mfma16(short8 a, short8 b, floatx4 c) {
  return __builtin_amdgcn_mfma_f32_16x16x32_bf16(a, b, c, 0, 0, 0);
}

#define LOG2E 1.4426950408889634f

// ---- kernel 1: self-scanning gather-prep (+ qc pack in extra blocks) --------
// R11: the separate scan kernel is gone. Each prep block recomputes the global
// prefix over used[] PRIVATELY: used (256 KB) stays hot in every XCD L2, so
// 1056 redundant scans cost ~8 us of L2 reads chip-wide — cheaper than one
// extra kernel launch (~20 us measured overhead/launch) plus the scan kernel.
// No cross-block ordering, no fences (R8 lesson).
// Masked slots contribute EXACTLY 0 to softmax (exp2(-1e9) underflows to 0 in
// fp32, same as the reference), so compacting to used slots is numerically
// exact up to fp32 summation order (~1e-7).
// blocks [0, NG_PAD): compacted K/ctx/V/bias dest groups
// blocks [NG_PAD, NG_PAD+NB_QC): qc pack

template<int NC>
__global__ __launch_bounds__(256) void
prep3(const float* __restrict__ q, const float* __restrict__ ctx,
      const float* __restrict__ keys, const float* __restrict__ ctxs,
      const float* __restrict__ vals, const float* __restrict__ ts,
      const int* __restrict__ used,
      unsigned short* __restrict__ qc, unsigned short* __restrict__ kc2,
      unsigned short* __restrict__ vt2, float* __restrict__ biasc,
      int* __restrict__ gtotal)
{
  const int bid = blockIdx.x;
  const int t = threadIdx.x;

  if (bid >= NG_PAD) {                 // qc pack path
    int tt = (bid - NG_PAD) * 256 + t; // 4096*96 = 1536*256
    int b = tt / KD, j = tt % KD;
    float v = (j < 64) ? q[b * 64 + j] : 0.5f * ctx[b * 32 + (j - 64)];
    qc[tt] = f2bf(v * LOG2E);
    return;
  }

  // ---- shared memory: region A (scan) overlaid by region B (gather) --------
  __shared__ __align__(16) char smem[25088];
  unsigned long long* smask = reinterpret_cast<unsigned long long*>(smem); // [1024] 8 KB
  int* soff = reinterpret_cast<int*>(smem + 8192);                         // [1024] 4 KB
  float* lk = reinterpret_cast<float*>(smem);            // [64][65] 16.6 KB (after scan)
  float* lx = reinterpret_cast<float*>(smem) + 64 * 65;  // [64][33]  8.4 KB
  __shared__ int sc[256];
  __shared__ int sidx[64];

  const int w = t >> 6, l = t & 63;

  // phase 1: ballot-pack used[] into per-group masks (8-deep load batching).
  // iteration j, wave w covers slots j*256 + w*64 + l -> group j*4 + w.
#pragma unroll 1
  for (int j0 = 0; j0 < 256; j0 += 8) {
    int v[8];
#pragma unroll
    for (int k = 0; k < 8; ++k)
      v[k] = used[(j0 + k) * 256 + t];
#pragma unroll
    for (int k = 0; k < 8; ++k) {
      unsigned long long m = __ballot(v[k] != 0);
      if (l == 0) smask[(j0 + k) * 4 + w] = m;
    }
  }
  __syncthreads();

  // phase 2: 256-thread prefix scan over 1024 group counts (4 per thread)
  int c4[4];
#pragma unroll
  for (int j = 0; j < 4; ++j) c4[j] = __popcll(smask[t * 4 + j]);
  int sum4 = c4[0] + c4[1] + c4[2] + c4[3];
  sc[t] = sum4;
  __syncthreads();
#pragma unroll 1
  for (int st = 1; st < 256; st <<= 1) {
    int add = (t >= st) ? sc[t - st] : 0;
    __syncthreads();
    sc[t] += add;
    __syncthreads();
  }
  {
    int run = sc[t] - sum4;            // exclusive prefix of this thread's 4 groups
#pragma unroll
    for (int j = 0; j < 4; ++j) { soff[t * 4 + j] = run; run += c4[j]; }
  }
  __syncthreads();

  const int total = soff[NGRP - 1] + __popcll(smask[NGRP - 1]);
  const int gq = bid;
  const int Gtot = (total + 63) >> 6;
  int GPC = (Gtot + NC - 1) / NC;
  if (GPC < 1) GPC = 1;
  const int glim = NC * GPC;           // groups flash will actually read

  if (bid == 0 && t == 0) *gtotal = total;
  if (gq >= glim) return;

  if (gq * 64 >= total) {              // full pad group: zeros + -1e9 bias
    short8 z8;
#pragma unroll
    for (int j = 0; j < 8; ++j) z8[j] = 0;
    unsigned short* outk = kc2 + (size_t)gq * 6144;
#pragma unroll
    for (int p = 0; p < 3; ++p)
      *reinterpret_cast<short8*>(outk + p * 2048 + t * 8) = z8;
    unsigned short* outv = vt2 + (size_t)gq * 4096;
#pragma unroll
    for (int p = 0; p < 2; ++p)
      *reinterpret_cast<short8*>(outv + p * 2048 + t * 8) = z8;
    if (t < 64) biasc[gq * 64 + t] = -1e9f;
    return;
  }

  // phase 3: source index for this dest group's 64 slots (LDS search)
  if (t < 64) {
    int mP = gq * 64 + t, src = -1;
    if (mP < total) {
      int lo = 0, hi = NGRP - 1;
#pragma unroll 1
      while (lo < hi) {                // last g with soff[g] <= mP
        int mid = (lo + hi + 1) >> 1;
        if (soff[mid] <= mP) lo = mid; else hi = mid - 1;
      }
      int r = mP - soff[lo];
      unsigned long long x = smask[lo];
#pragma unroll 1
      for (int k = 0; k < r; ++k) x &= x - 1;   // select r-th set bit
      src = lo * 64 + (int)__builtin_ctzll(x);
    }
    sidx[t] = src;
  }
  __syncthreads();   // sidx ready; region A no longer needed -> reuse as lk/lx

  const floatx4* kb4 = reinterpret_cast<const floatx4*>(keys);
  const floatx4* xb4 = reinterpret_cast<const floatx4*>(ctxs);
  const floatx4* vb4 = reinterpret_cast<const floatx4*>(vals);
  floatx4 z4; z4[0] = 0.f; z4[1] = 0.f; z4[2] = 0.f; z4[3] = 0.f;

  // gather K rows (64x64 f32) + ctx rows (64x32 f32); pad rows -> 0
#pragma unroll
  for (int i = 0; i < 4; ++i) {
    int idx4 = i * 256 + t;
    int row = idx4 >> 4, col = idx4 & 15;
    int s = sidx[row];
    floatx4 v = (s >= 0) ? kb4[(size_t)s * 16 + col] : z4;
    lk[row * 65 + col * 4 + 0] = v[0];
    lk[row * 65 + col * 4 + 1] = v[1];
    lk[row * 65 + col * 4 + 2] = v[2];
    lk[row * 65 + col * 4 + 3] = v[3];
  }
#pragma unroll
  for (int i = 0; i < 2; ++i) {
    int idx4 = i * 256 + t;
    int row = idx4 >> 3, col = idx4 & 7;
    int s = sidx[row];
    floatx4 v = (s >= 0) ? xb4[(size_t)s * 8 + col] : z4;
    lx[row * 33 + col * 4 + 0] = v[0];
    lx[row * 33 + col * 4 + 1] = v[1];
    lx[row * 33 + col * 4 + 2] = v[2];
    lx[row * 33 + col * 4 + 3] = v[3];
  }
  __syncthreads();

  // pack kc2 fragment-linear (A-operand of S^T = K*Q^T), dest group gq
  unsigned short* outk = kc2 + (size_t)gq * 6144;
#pragma unroll
  for (int p = 0; p < 3; ++p) {
    int o = p * 2048 + t * 8;
    int c = o >> 9;
    int lane = (o >> 3) & 63;
    int lqq = lane >> 4, lcc = lane & 15;
    int nt = c / 3, s = c - nt * 3;
    int ml = nt * 16 + lcc;
    short8 v;
#pragma unroll
    for (int j = 0; j < 8; ++j) {
      int kk = s * 32 + lqq * 8 + j;
      float f = (kk < 64) ? lk[ml * 65 + kk] : lx[ml * 33 + (kk - 64)];
      v[j] = (short)f2bf(f);
    }
    *reinterpret_cast<short8*>(outk + o) = v;
  }
  // bias for this dest group (pad -> -1e9 -> exp2 -> 0)
  if (t < 64) {
    int s = sidx[t];
    biasc[gq * 64 + t] =
        (s >= 0) ? (LOG2E * 0.3f * __expf(-0.1f * (1.0f - ts[s])) - SHIFT2)
                 : -1e9f;
  }
  __syncthreads();   // all kc2-pack reads of lk done before V overwrites it

  // gather V rows into lk
#pragma unroll
  for (int i = 0; i < 4; ++i) {
    int idx4 = i * 256 + t;
    int row = idx4 >> 4, col = idx4 & 15;
    int s = sidx[row];
    floatx4 v = (s >= 0) ? vb4[(size_t)s * 16 + col] : z4;
    lk[row * 65 + col * 4 + 0] = v[0];
    lk[row * 65 + col * 4 + 1] = v[1];
    lk[row * 65 + col * 4 + 2] = v[2];
    lk[row * 65 + col * 4 + 3] = v[3];
  }
  __syncthreads();

  // pack vt2 (B-operand of P*V, key-permutation baked in), dest group gq
  unsigned short* outv = vt2 + (size_t)gq * 4096;
#pragma unroll
  for (int p = 0; p < 2; ++p) {
    int o = p * 2048 + t * 8;
    int c2 = o >> 9;
    int lane = (o >> 3) & 63;
    int lqq = lane >> 4, lcc = lane & 15;
    int h = c2 >> 2, nd = c2 & 3;
    short8 wv;
#pragma unroll
    for (int j = 0; j < 8; ++j) {
      int mloc = h * 32 + ((j < 4) ? (lqq * 4 + j) : (16 + lqq * 4 + (j - 4)));
      wv[j] = (short)f2bf(lk[mloc * 65 + nd * 16 + lcc]);
    }
    *reinterpret_cast<short8*>(outv + o) = wv;
  }
}

// ---- kernel 2: flash attention (R7/R10-proven structure) --------------------
// grid (NQT, NC); block 256 = 4 waves; each wave owns 32 q rows (2 B-frags).
// Runs over the COMPACTED slot stream: NIT = GPC = ceil(Gtot/NC) groups per
// chunk (gtotal read at runtime; uniform across grid; grid static -> graph-
// capture safe). Software pipeline + setprio (R5). NO in-kernel device fences
// (R8 lesson: per-block threadfence = L2 writeback storm; kernel-boundary
// sync is cheaper).

template<int NC>
__global__ __launch_bounds__(256, 4) void
flash_kernel(const unsigned short* __restrict__ qc,
             const unsigned short* __restrict__ kc2,
             const unsigned short* __restrict__ vt2,
             const float* __restrict__ biasc,
             const int* __restrict__ gtotal,
             float* __restrict__ opart, float* __restrict__ lpart)
{
  __shared__ __align__(16) unsigned short lds_kv[2 * 10240];  // 40960 B
  const int qt    = blockIdx.x;
  const int chunk = blockIdx.y;
  const int tid   = threadIdx.x;
  const int w     = tid >> 6;
  const int lane  = tid & 63;
  const int lq    = lane >> 4;
  const int lc    = lane & 15;

  const int total = *gtotal;
  const int Gtot  = (total + 63) >> 6;
  int GPC = (Gtot + NC - 1) / NC;
  if (GPC < 1) GPC = 1;
  const int NIT = GPC;                 // 64-key tiles for this chunk
  const int g0  = chunk * GPC;

  floatx4 zero; zero[0] = 0.f; zero[1] = 0.f; zero[2] = 0.f; zero[3] = 0.f;

  // Q fragments (B-operand): q-rows qt*128 + w*32 + a*16 + lc
  short8 qf[2][3];
#pragma unroll
  for (int a = 0; a < 2; ++a) {
    const unsigned short* qrp = qc + (size_t)(qt * BQ + w * 32 + a * 16 + lc) * KD + lq * 8;
    qf[a][0] = *reinterpret_cast<const short8*>(qrp);
    qf[a][1] = *reinterpret_cast<const short8*>(qrp + 32);
    qf[a][2] = *reinterpret_cast<const short8*>(qrp + 64);
  }

  short8 ones;
#pragma unroll
  for (int i = 0; i < 8; ++i) ones[i] = (short)0x3F80;  // bf16 1.0

  const float* bptr = biasc + (size_t)g0 * 64 + lq * 4;

  // cooperative stage of one 64-key group: 20 x 1KB pieces, 5 per wave
  auto stage = [&](int it, int buf) {
    const unsigned short* kg = kc2 + (size_t)(g0 + it) * 6144;
    const unsigned short* vg = vt2 + (size_t)(g0 + it) * 4096;
    unsigned short* lb = lds_kv + buf * 10240;
#pragma unroll
    for (int j5 = 0; j5 < 5; ++j5) {
      int j = w + j5 * 4;
      const unsigned short* src = (j < 12) ? (kg + j * 512) : (vg + (j - 12) * 512);
      __builtin_amdgcn_global_load_lds(
          (const __attribute__((address_space(1))) void*)(src + lane * 8),
          (__attribute__((address_space(3))) void*)(lb + j * 512),
          16, 0, 0);
    }
  };

  floatx4 o[2][4];
#pragma unroll
  for (int a = 0; a < 2; ++a)
#pragma unroll
    for (int nd = 0; nd < 4; ++nd) o[a][nd] = zero;
  floatx4 lacc[2] = {zero, zero};
  int4v pk[2][2];

  // QK + exp2 + pack phase (fills pk; accumulates row sums via ones-MFMA)
  auto qk_phase = [&](const unsigned short* lb, const float* bp) {
    floatx4 b4v[4];
#pragma unroll
    for (int nt = 0; nt < 4; ++nt)
      b4v[nt] = *reinterpret_cast<const floatx4*>(bp + nt * 16);
#pragma unroll
    for (int nt = 0; nt < 4; ++nt) {
      short8 k0 = *reinterpret_cast<const short8*>(lb + (nt * 3 + 0) * 512 + lane * 8);
      short8 k1 = *reinterpret_cast<const short8*>(lb + (nt * 3 + 1) * 512 + lane * 8);
      short8 k2 = *reinterpret_cast<const short8*>(lb + (nt * 3 + 2) * 512 + lane * 8);
#pragma unroll
      for (int a = 0; a < 2; ++a) {
        floatx4 acc = b4v[nt];
        __builtin_amdgcn_s_setprio(1);
        acc = mfma16(k0, qf[a][0], acc);
        acc = mfma16(k1, qf[a][1], acc);
        acc = mfma16(k2, qf[a][2], acc);
        __builtin_amdgcn_s_setprio(0);
        float p0 = __builtin_amdgcn_exp2f(acc[0]);
        float p1 = __builtin_amdgcn_exp2f(acc[1]);
        float p2 = __builtin_amdgcn_exp2f(acc[2]);
        float p3 = __builtin_amdgcn_exp2f(acc[3]);
        pk[a][nt >> 1][(nt & 1) * 2]     = pack_bf16(p0, p1);
        pk[a][nt >> 1][(nt & 1) * 2 + 1] = pack_bf16(p2, p3);
      }
    }
    __builtin_amdgcn_s_setprio(1);
#pragma unroll
    for (int a = 0; a < 2; ++a) {
      lacc[a] = mfma16(__builtin_bit_cast(short8, pk[a][0]), ones, lacc[a]);
      lacc[a] = mfma16(__builtin_bit_cast(short8, pk[a][1]), ones, lacc[a]);
    }
    __builtin_amdgcn_s_setprio(0);
  };

  // PV phase for the pk currently in registers, V frags from given buffer
  auto pv_phase = [&](const unsigned short* lb) {
    __builtin_amdgcn_s_setprio(1);
#pragma unroll
    for (int nd = 0; nd < 4; ++nd) {
      short8 v0 = *reinterpret_cast<const short8*>(lb + 6144 + nd * 512 + lane * 8);
      short8 v1 = *reinterpret_cast<const short8*>(lb + 6144 + (4 + nd) * 512 + lane * 8);
#pragma unroll
      for (int a = 0; a < 2; ++a) {
        o[a][nd] = mfma16(__builtin_bit_cast(short8, pk[a][0]), v0, o[a][nd]);
        o[a][nd] = mfma16(__builtin_bit_cast(short8, pk[a][1]), v1, o[a][nd]);
      }
    }
    __builtin_amdgcn_s_setprio(0);
  };

  // prologue (stage(1) safe even when NIT==1: group g0+1 <= NC*GPC < NG_PAD,
  // in-bounds; its data is only consumed when NIT >= 2)
  stage(0, 0);
  __syncthreads();                  // stage(0) landed
  stage(1, 1);
  qk_phase(lds_kv, bptr);
  bptr += BN;

#pragma unroll 1
  for (int it = 1; it < NIT; ++it) {
    // PV for iter it-1: buffer (it-1)&1 still valid (stage(it+1) not yet issued)
    pv_phase(lds_kv + ((it - 1) & 1) * 10240);
    __syncthreads();               // drains PV ds_reads + stage(it) vmcnt
    if (it + 1 < NIT) stage(it + 1, (it + 1) & 1);
    qk_phase(lds_kv + (it & 1) * 10240, bptr);
    bptr += BN;
  }
  pv_phase(lds_kv + ((NIT - 1) & 1) * 10240);

  // epilogue: write partial O and l
  const int pb = qt * NC + chunk;
  float* op = opart + (size_t)pb * BQ * D_V;
#pragma unroll
  for (int a = 0; a < 2; ++a) {
    const int rbase = w * 32 + a * 16 + lq * 4;
#pragma unroll
    for (int nd = 0; nd < 4; ++nd)
#pragma unroll
      for (int r = 0; r < 4; ++r)
        op[(rbase + r) * D_V + nd * 16 + lc] = o[a][nd][r];
    // lacc C-layout: lane (lq,lc) reg r holds l[q-row = lq*4+r] (same across lc)
    if (lc == 0) {
      float* lp = lpart + (size_t)pb * BQ;
#pragma unroll
      for (int r = 0; r < 4; ++r) lp[rbase + r] = lacc[a][r];
    }
  }
}

// ---- kernel 3: final reduction (float4-vectorized) --------------------------

template<int NC>
__global__ void reduce_out(const float* __restrict__ opart, const float* __restrict__ lpart,
                           float* __restrict__ out) {
  int t = blockIdx.x * 256 + threadIdx.x;   // 65536 float4s total
  int d4 = t & 15;
  int b = t >> 4;            // q-row 0..4095
  int qt = b >> 7, r = b & 127;
  const floatx4* op4 = reinterpret_cast<const floatx4*>(opart);
  floatx4 os; os[0] = 0.f; os[1] = 0.f; os[2] = 0.f; os[3] = 0.f;
  float ls = 0.f;
#pragma unroll
  for (int c = 0; c < NC; ++c) {
    int row = (qt * NC + c) * BQ + r;
    os += op4[(size_t)row * 16 + d4];
    ls += lpart[row];
  }
  float inv = 1.0f / ls;
  reinterpret_cast<floatx4*>(out)[t] = os * inv;
}

// ---- launcher ---------------------------------------------------------------

template<int NC>
static void launch_all(const float* query, const float* context, const float* keys,
                       const float* values, const float* contexts, const float* ts,
                       const int* used, float* out, char* ws, hipStream_t stream) {
  unsigned short* qc   = (unsigned short*)ws;  ws += (size_t)B_TOT * KD * 2;
  unsigned short* kc2c = (unsigned short*)ws;  ws += (size_t)NG_PAD * 6144 * 2;
  unsigned short* vt2c = (unsigned short*)ws;  ws += (size_t)NG_PAD * 4096 * 2;
  float* biasc = (float*)ws;                   ws += (size_t)NG_PAD * 64 * 4;
  int* gtotal  = (int*)ws;                     ws += 16;
  float* opart = (float*)ws;                   ws += (size_t)NC * B_TOT * D_V * 4;
  float* lpart = (float*)ws;

  prep3<NC><<<NG_PAD + NB_QC, 256, 0, stream>>>(
      query, context, keys, contexts, values, ts, used,
      qc, kc2c, vt2c, biasc, gtotal);

  dim3 grid(NQT, NC);
  flash_kernel<NC><<<grid, 256, 0, stream>>>(qc, kc2c, vt2c, biasc, gtotal,
                                             opart, lpart);

  reduce_out<NC><<<(B_TOT * D_V / 4) / 256, 256, 0, stream>>>(opart, lpart, out);
}

extern "C" void kernel_launch(void* const* d_in, const int* in_sizes, int n_in,
                              void* d_out, int out_size, void* d_ws, size_t ws_size,
                              hipStream_t stream) {
  const float* query    = (const float*)d_in[0];
  const float* context  = (const float*)d_in[1];
  const float* keys     = (const float*)d_in[2];
  const float* values   = (const float*)d_in[3];
  const float* contexts = (const float*)d_in[4];
  const float* ts       = (const float*)d_in[5];
  const int*   used     = (const int*)d_in[6];
  float* out = (float*)d_out;
  char* ws = (char*)d_ws;

  const size_t fixed = (size_t)B_TOT * KD * 2 + (size_t)NG_PAD * 6144 * 2 +
                       (size_t)NG_PAD * 4096 * 2 + (size_t)NG_PAD * 64 * 4 + 16;
  const size_t need32 = fixed + 32ull * ((size_t)B_TOT * D_V * 4 + (size_t)B_TOT * 4);

  if (ws_size >= need32)
    launch_all<32>(query, context, keys, values, contexts, ts, used, out, ws, stream);
  else
    launch_all<16>(query, context, keys, values, contexts, ts, used, out, ws, stream);
}